// Round 1
// baseline (653.540 us; speedup 1.0000x reference)
//
#include <hip/hip_runtime.h>

#define NH 128

// ---------------------------------------------------------------------------
// 1) Exclusive prefix scan of grid_sizes -> c[0..G], c[G] = total
// ---------------------------------------------------------------------------
__global__ void scan_kernel(const int* __restrict__ gs, int* __restrict__ c, int G) {
    __shared__ int part[1024];
    int t = threadIdx.x;
    int chunk = (G + 1023) >> 10;
    int b = t * chunk;
    int e = min(b + chunk, G);
    int s = 0;
    for (int i = b; i < e; ++i) s += gs[i];
    part[t] = s;
    __syncthreads();
    for (int off = 1; off < 1024; off <<= 1) {
        int val = (t >= off) ? part[t - off] : 0;
        __syncthreads();
        part[t] += val;
        __syncthreads();
    }
    int excl = (t == 0) ? 0 : part[t - 1];
    for (int i = b; i < e; ++i) { c[i] = excl; excl += gs[i]; }
    if (t == 1023) c[G] = part[1023];
}

// ---------------------------------------------------------------------------
// 2a) A = Wk @ Wi  (A[e,d] = sum_f Wk[e,f]*Wi[f,d]),  u = Wk @ bi
// ---------------------------------------------------------------------------
__global__ void matA_kernel(const float* __restrict__ Wk, const float* __restrict__ Wi,
                            const float* __restrict__ bi,
                            float* __restrict__ A, float* __restrict__ u) {
    int tid = blockIdx.x * blockDim.x + threadIdx.x;  // 0..NH*NH-1
    int e = tid >> 7, d = tid & (NH - 1);
    float acc = 0.f;
    for (int f = 0; f < NH; ++f) acc += Wk[e * NH + f] * Wi[f * NH + d];
    A[e * NH + d] = acc;
    if (tid < NH) {
        float s = 0.f;
        for (int f = 0; f < NH; ++f) s += Wk[tid * NH + f] * bi[f];
        u[tid] = s;
    }
}

// ---------------------------------------------------------------------------
// 2b) B = Wi^T @ A stored transposed: Bt[f*NH+d] = B[d,f] = sum_e Wi[e,d]*A[e,f]
//     v = Wi^T @ u,  w[f] = sum_e bi[e]*A[e,f],  s0 = bi.u + bk
// ---------------------------------------------------------------------------
__global__ void matB_kernel(const float* __restrict__ Wi, const float* __restrict__ bi,
                            const float* __restrict__ bk,
                            const float* __restrict__ A, const float* __restrict__ u,
                            float* __restrict__ Bt, float* __restrict__ v,
                            float* __restrict__ w, float* __restrict__ s0) {
    int tid = blockIdx.x * blockDim.x + threadIdx.x;
    int i = tid & (NH - 1);   // d (inner, coalesced)
    int j = tid >> 7;         // f
    float acc = 0.f;
    for (int e = 0; e < NH; ++e) acc += Wi[e * NH + i] * A[e * NH + j];
    Bt[j * NH + i] = acc;
    if (tid < NH) {
        float s = 0.f;
        for (int e = 0; e < NH; ++e) s += Wi[e * NH + tid] * u[e];
        v[tid] = s;
    } else if (tid < 2 * NH) {
        int jj = tid - NH;
        float s = 0.f;
        for (int e = 0; e < NH; ++e) s += bi[e] * A[e * NH + jj];
        w[jj] = s;
    }
    if (tid == 0) {
        float s = 0.f;
        for (int e = 0; e < NH; ++e) s += bi[e] * u[e];
        s0[0] = s + bk[0];
    }
}

// ---------------------------------------------------------------------------
// 3) Per-segment: m_g = mean of gathered embedding_ rows;
//    Q[g] = B @ m_g + v ; C2[g] = w . m_g + s0
//    8 segments per block (amortizes Bt traffic), 128 threads (thread = dim d)
// ---------------------------------------------------------------------------
#define SEGS_PER_BLOCK 8
__global__ void seg_kernel(const float* __restrict__ emb_, const int* __restrict__ pos,
                           const int* __restrict__ c,
                           const float* __restrict__ Bt, const float* __restrict__ v,
                           const float* __restrict__ w, const float* __restrict__ s0,
                           float* __restrict__ Q, float* __restrict__ C2, int G) {
    __shared__ float m[SEGS_PER_BLOCK][NH];
    __shared__ float red[SEGS_PER_BLOCK][2];
    int d = threadIdx.x;  // 0..127
    int g0 = blockIdx.x * SEGS_PER_BLOCK;
    int ns = min(SEGS_PER_BLOCK, G - g0);

    for (int s = 0; s < SEGS_PER_BLOCK; ++s) {
        float acc = 0.f;
        if (s < ns) {
            int b = c[g0 + s], e = c[g0 + s + 1];
            for (int i = b; i < e; ++i)
                acc += emb_[(size_t)pos[i] * NH + d];
            acc /= (float)(e - b);
        }
        m[s][d] = acc;
    }
    __syncthreads();

    float q[SEGS_PER_BLOCK];
#pragma unroll
    for (int s = 0; s < SEGS_PER_BLOCK; ++s) q[s] = 0.f;
    for (int f = 0; f < NH; ++f) {
        float bt = Bt[f * NH + d];          // coalesced, L1/L2-hot
#pragma unroll
        for (int s = 0; s < SEGS_PER_BLOCK; ++s) q[s] += bt * m[s][f];  // LDS broadcast
    }
    float vd = v[d], wd = w[d], s00 = s0[0];
    for (int s = 0; s < ns; ++s)
        Q[(size_t)(g0 + s) * NH + d] = q[s] + vd;

    int lane = d & 63, wv = d >> 6;
    for (int s = 0; s < SEGS_PER_BLOCK; ++s) {
        float t = wd * m[s][d];
        for (int off = 32; off; off >>= 1) t += __shfl_xor(t, off);
        if (lane == 0) red[s][wv] = t;
    }
    __syncthreads();
    if (d < SEGS_PER_BLOCK && d < ns) C2[g0 + d] = red[d][0] + red[d][1] + s00;
}

// ---------------------------------------------------------------------------
// 4) Logits: block per segment; one wave per sample; out = x . q_g + c2_g
// ---------------------------------------------------------------------------
__global__ void logits_kernel(const float* __restrict__ emb, const int* __restrict__ pos,
                              const int* __restrict__ neg, const int* __restrict__ c,
                              const float* __restrict__ Q, const float* __restrict__ C2,
                              float* __restrict__ out, int P, int ratio) {
    __shared__ float q[NH];
    int g = blockIdx.x;
    int t = threadIdx.x;
    if (t < NH) q[t] = Q[(size_t)g * NH + t];
    __syncthreads();
    float c2 = C2[g];
    int pb = c[g], pe = c[g + 1];
    int wv = t >> 6, lane = t & 63;
    float q0 = q[2 * lane], q1 = q[2 * lane + 1];

    for (int i = pb + wv; i < pe; i += 4) {
        const float2 a = ((const float2*)(emb + (size_t)pos[i] * NH))[lane];
        float val = a.x * q0 + a.y * q1;
        for (int off = 32; off; off >>= 1) val += __shfl_xor(val, off);
        if (lane == 0) out[i] = val + c2;
    }
    int nb = pb * ratio, ne = pe * ratio;
    for (int j = nb + wv; j < ne; j += 4) {
        const float2 a = ((const float2*)(emb + (size_t)neg[j] * NH))[lane];
        float val = a.x * q0 + a.y * q1;
        for (int off = 32; off; off >>= 1) val += __shfl_xor(val, off);
        if (lane == 0) out[P + j] = val + c2;
    }
}

// ---------------------------------------------------------------------------
extern "C" void kernel_launch(void* const* d_in, const int* in_sizes, int n_in,
                              void* d_out, int out_size, void* d_ws, size_t ws_size,
                              hipStream_t stream) {
    const float* embedding  = (const float*)d_in[0];
    const float* embedding_ = (const float*)d_in[1];
    const int*   grid_sizes = (const int*)d_in[2];
    const int*   pos        = (const int*)d_in[3];
    const int*   neg        = (const int*)d_in[4];
    const float* Wi         = (const float*)d_in[5];
    const float* bi         = (const float*)d_in[6];
    const float* Wk         = (const float*)d_in[7];
    const float* bk         = (const float*)d_in[8];

    int G = in_sizes[2];
    int P = in_sizes[3];
    int PN = in_sizes[4];
    int ratio = PN / P;

    char* ws = (char*)d_ws;
    size_t off = 0;
    auto alloc = [&](size_t bytes) {
        void* p = ws + off;
        off += (bytes + 255) & ~(size_t)255;
        return p;
    };
    int*   c   = (int*)  alloc((size_t)(G + 1) * sizeof(int));
    float* A   = (float*)alloc(NH * NH * sizeof(float));
    float* u   = (float*)alloc(NH * sizeof(float));
    float* Bt  = (float*)alloc(NH * NH * sizeof(float));
    float* v   = (float*)alloc(NH * sizeof(float));
    float* w   = (float*)alloc(NH * sizeof(float));
    float* s0  = (float*)alloc(sizeof(float));
    float* Q   = (float*)alloc((size_t)G * NH * sizeof(float));
    float* C2  = (float*)alloc((size_t)G * sizeof(float));
    (void)ws_size; (void)n_in; (void)out_size;

    hipLaunchKernelGGL(scan_kernel, dim3(1), dim3(1024), 0, stream, grid_sizes, c, G);
    hipLaunchKernelGGL(matA_kernel, dim3((NH * NH) / 256), dim3(256), 0, stream,
                       Wk, Wi, bi, A, u);
    hipLaunchKernelGGL(matB_kernel, dim3((NH * NH) / 256), dim3(256), 0, stream,
                       Wi, bi, bk, A, u, Bt, v, w, s0);
    hipLaunchKernelGGL(seg_kernel, dim3((G + SEGS_PER_BLOCK - 1) / SEGS_PER_BLOCK), dim3(NH), 0, stream,
                       embedding_, pos, c, Bt, v, w, s0, Q, C2, G);
    hipLaunchKernelGGL(logits_kernel, dim3(G), dim3(256), 0, stream,
                       embedding, pos, neg, c, Q, C2, (float*)d_out, P, ratio);
}

// Round 2
// 541.627 us; speedup vs baseline: 1.2066x; 1.2066x over previous
//
#include <hip/hip_runtime.h>

#define NH 128

// ---------------------------------------------------------------------------
// 1) Exclusive prefix scan of grid_sizes -> c[0..G], c[G] = total
// ---------------------------------------------------------------------------
__global__ void scan_kernel(const int* __restrict__ gs, int* __restrict__ c, int G) {
    __shared__ int part[1024];
    int t = threadIdx.x;
    int chunk = (G + 1023) >> 10;
    int b = t * chunk;
    int e = min(b + chunk, G);
    int s = 0;
    for (int i = b; i < e; ++i) s += gs[i];
    part[t] = s;
    __syncthreads();
    for (int off = 1; off < 1024; off <<= 1) {
        int val = (t >= off) ? part[t - off] : 0;
        __syncthreads();
        part[t] += val;
        __syncthreads();
    }
    int excl = (t == 0) ? 0 : part[t - 1];
    for (int i = b; i < e; ++i) { c[i] = excl; excl += gs[i]; }
    if (t == 1023) c[G] = part[1023];
}

// ---------------------------------------------------------------------------
// 2a) A = Wk @ Wi,  u = Wk @ bi
// ---------------------------------------------------------------------------
__global__ void matA_kernel(const float* __restrict__ Wk, const float* __restrict__ Wi,
                            const float* __restrict__ bi,
                            float* __restrict__ A, float* __restrict__ u) {
    int tid = blockIdx.x * blockDim.x + threadIdx.x;  // 0..NH*NH-1
    int e = tid >> 7, d = tid & (NH - 1);
    float acc = 0.f;
    for (int f = 0; f < NH; ++f) acc += Wk[e * NH + f] * Wi[f * NH + d];
    A[e * NH + d] = acc;
    if (tid < NH) {
        float s = 0.f;
        for (int f = 0; f < NH; ++f) s += Wk[tid * NH + f] * bi[f];
        u[tid] = s;
    }
}

// ---------------------------------------------------------------------------
// 2b) Bt[f*NH+d] = sum_e Wi[e,d]*A[e,f];  v = Wi^T u;  w[f] = bi.A[:,f];
//     s0 = bi.u + bk
// ---------------------------------------------------------------------------
__global__ void matB_kernel(const float* __restrict__ Wi, const float* __restrict__ bi,
                            const float* __restrict__ bk,
                            const float* __restrict__ A, const float* __restrict__ u,
                            float* __restrict__ Bt, float* __restrict__ v,
                            float* __restrict__ w, float* __restrict__ s0) {
    int tid = blockIdx.x * blockDim.x + threadIdx.x;
    int i = tid & (NH - 1);
    int j = tid >> 7;
    float acc = 0.f;
    for (int e = 0; e < NH; ++e) acc += Wi[e * NH + i] * A[e * NH + j];
    Bt[j * NH + i] = acc;
    if (tid < NH) {
        float s = 0.f;
        for (int e = 0; e < NH; ++e) s += Wi[e * NH + tid] * u[e];
        v[tid] = s;
    } else if (tid < 2 * NH) {
        int jj = tid - NH;
        float s = 0.f;
        for (int e = 0; e < NH; ++e) s += bi[e] * A[e * NH + jj];
        w[jj] = s;
    }
    if (tid == 0) {
        float s = 0.f;
        for (int e = 0; e < NH; ++e) s += bi[e] * u[e];
        s0[0] = s + bk[0];
    }
}

// ---------------------------------------------------------------------------
// 3) seg_mean: one block per segment; 8 row-slots x 32 lanes; float4 row loads.
//    M[g][d] = mean over rows of embedding_[pos[.]][d]
// ---------------------------------------------------------------------------
__global__ void seg_mean_kernel(const float* __restrict__ emb_, const int* __restrict__ pos,
                                const int* __restrict__ c, float* __restrict__ M, int G) {
    __shared__ float smf[8 * NH];
    int g = blockIdx.x;
    int t = threadIdx.x;            // 256
    int lane = t & 31, slot = t >> 5;
    int b = c[g], e = c[g + 1];
    float4 acc = make_float4(0.f, 0.f, 0.f, 0.f);
    for (int r = b + slot; r < e; r += 8) {
        int row = pos[r];
        const float4 a = ((const float4*)(emb_ + (size_t)row * NH))[lane];
        acc.x += a.x; acc.y += a.y; acc.z += a.z; acc.w += a.w;
    }
    ((float4*)(smf + slot * NH))[lane] = acc;
    __syncthreads();
    if (t < NH) {
        float s = 0.f;
#pragma unroll
        for (int s2 = 0; s2 < 8; ++s2) s += smf[s2 * NH + t];
        float cnt = (float)max(e - b, 1);
        M[(size_t)g * NH + t] = s / cnt;
    }
}

// ---------------------------------------------------------------------------
// 4) q_kernel: Q[g] = B @ M[g] + v ; C2[g] = w . M[g] + s0   (8 segs / block)
// ---------------------------------------------------------------------------
#define SPB 8
__global__ void q_kernel(const float* __restrict__ M, const float* __restrict__ Bt,
                         const float* __restrict__ v, const float* __restrict__ w,
                         const float* __restrict__ s0,
                         float* __restrict__ Q, float* __restrict__ C2, int G) {
    __shared__ float m[SPB][NH];
    __shared__ float red[SPB][2];
    int d = threadIdx.x;            // 128
    int g0 = blockIdx.x * SPB;
    int ns = min(SPB, G - g0);
    for (int s = 0; s < SPB; ++s)
        m[s][d] = (s < ns) ? M[(size_t)(g0 + s) * NH + d] : 0.f;
    __syncthreads();

    float q[SPB];
#pragma unroll
    for (int s = 0; s < SPB; ++s) q[s] = 0.f;
    for (int f = 0; f < NH; ++f) {
        float bt = Bt[f * NH + d];
#pragma unroll
        for (int s = 0; s < SPB; ++s) q[s] += bt * m[s][f];
    }
    float vd = v[d], wd = w[d], s00 = s0[0];
    for (int s = 0; s < ns; ++s)
        Q[(size_t)(g0 + s) * NH + d] = q[s] + vd;

    int lane = d & 63, wv = d >> 6;
    for (int s = 0; s < SPB; ++s) {
        float tval = wd * m[s][d];
        for (int off = 32; off; off >>= 1) tval += __shfl_xor(tval, off);
        if (lane == 0) red[s][wv] = tval;
    }
    __syncthreads();
    if (d < SPB && d < ns) C2[g0 + d] = red[d][0] + red[d][1] + s00;
}

// ---------------------------------------------------------------------------
// 5) logits: block per segment; 8 half-wave (32-lane) sample slots; indices
//    staged in LDS; float4 row loads; out = x . q_g + c2_g
// ---------------------------------------------------------------------------
__global__ void logits_kernel(const float* __restrict__ emb, const int* __restrict__ pos,
                              const int* __restrict__ neg, const int* __restrict__ c,
                              const float* __restrict__ Q, const float* __restrict__ C2,
                              float* __restrict__ out, int P, int ratio) {
    __shared__ float qs[NH];
    __shared__ int idx[512];
    int g = blockIdx.x;
    int t = threadIdx.x;            // 256
    if (t < NH) qs[t] = Q[(size_t)g * NH + t];
    int pb = c[g], pe = c[g + 1];
    int np = pe - pb;
    int nb = pb * ratio;
    int tot = np + np * ratio;
    int lane = t & 31, slot = t >> 5;
    __syncthreads();
    float4 qr = ((const float4*)qs)[lane];
    float c2 = C2[g];

    for (int k0 = 0; k0 < tot; k0 += 512) {
        int kend = min(tot - k0, 512);
        __syncthreads();
        for (int k = t; k < kend; k += 256) {
            int kk = k0 + k;
            idx[k] = (kk < np) ? pos[pb + kk] : neg[nb + kk - np];
        }
        __syncthreads();
        for (int k = slot; k < kend; k += 8) {
            int kk = k0 + k;
            int row = idx[k];
            const float4 a = ((const float4*)(emb + (size_t)row * NH))[lane];
            float val = a.x * qr.x + a.y * qr.y + a.z * qr.z + a.w * qr.w;
#pragma unroll
            for (int off = 16; off; off >>= 1) val += __shfl_xor(val, off, 32);
            if (lane == 0) {
                int o = (kk < np) ? (pb + kk) : (P + nb + kk - np);
                out[o] = val + c2;
            }
        }
    }
}

// ---------------------------------------------------------------------------
extern "C" void kernel_launch(void* const* d_in, const int* in_sizes, int n_in,
                              void* d_out, int out_size, void* d_ws, size_t ws_size,
                              hipStream_t stream) {
    const float* embedding  = (const float*)d_in[0];
    const float* embedding_ = (const float*)d_in[1];
    const int*   grid_sizes = (const int*)d_in[2];
    const int*   pos        = (const int*)d_in[3];
    const int*   neg        = (const int*)d_in[4];
    const float* Wi         = (const float*)d_in[5];
    const float* bi         = (const float*)d_in[6];
    const float* Wk         = (const float*)d_in[7];
    const float* bk         = (const float*)d_in[8];

    int G = in_sizes[2];
    int P = in_sizes[3];
    int PN = in_sizes[4];
    int ratio = PN / P;

    char* ws = (char*)d_ws;
    size_t off = 0;
    auto alloc = [&](size_t bytes) {
        void* p = ws + off;
        off += (bytes + 255) & ~(size_t)255;
        return p;
    };
    int*   c   = (int*)  alloc((size_t)(G + 1) * sizeof(int));
    float* A   = (float*)alloc(NH * NH * sizeof(float));
    float* u   = (float*)alloc(NH * sizeof(float));
    float* Bt  = (float*)alloc(NH * NH * sizeof(float));
    float* v   = (float*)alloc(NH * sizeof(float));
    float* w   = (float*)alloc(NH * sizeof(float));
    float* s0  = (float*)alloc(sizeof(float));
    float* Q   = (float*)alloc((size_t)G * NH * sizeof(float));
    float* C2  = (float*)alloc((size_t)G * sizeof(float));
    float* M   = (float*)alloc((size_t)G * NH * sizeof(float));
    (void)ws_size; (void)n_in; (void)out_size;

    hipLaunchKernelGGL(scan_kernel, dim3(1), dim3(1024), 0, stream, grid_sizes, c, G);
    hipLaunchKernelGGL(matA_kernel, dim3((NH * NH) / 256), dim3(256), 0, stream,
                       Wk, Wi, bi, A, u);
    hipLaunchKernelGGL(matB_kernel, dim3((NH * NH) / 256), dim3(256), 0, stream,
                       Wi, bi, bk, A, u, Bt, v, w, s0);
    hipLaunchKernelGGL(seg_mean_kernel, dim3(G), dim3(256), 0, stream,
                       embedding_, pos, c, M, G);
    hipLaunchKernelGGL(q_kernel, dim3((G + SPB - 1) / SPB), dim3(NH), 0, stream,
                       M, Bt, v, w, s0, Q, C2, G);
    hipLaunchKernelGGL(logits_kernel, dim3(G), dim3(256), 0, stream,
                       embedding, pos, neg, c, Q, C2, (float*)d_out, P, ratio);
}